// Round 1
// baseline (340.012 us; speedup 1.0000x reference)
//
#include <hip/hip_runtime.h>
#include <hip/hip_bf16.h>

#define TSTEPS 64
#define NTOT   8192
#define FDIM   256
#define HDIM   256
#define ROWS   32
#define NTHR   256

typedef __attribute__((ext_vector_type(8))) short bf16x8;
typedef __attribute__((ext_vector_type(4))) float f32x4;

__device__ __forceinline__ short f2bf(float f) {
    union { float f; unsigned u; } v; v.f = f;
    unsigned r = v.u + 0x7FFFu + ((v.u >> 16) & 1u);
    return (short)(r >> 16);
}

// One block owns ROWS=32 rows of N for all T steps. 4 waves; wave w computes
// output cols [64w, 64w+64). Weights live entirely in registers as MFMA
// B-fragments (wave only needs its 64 cols x K=256 of each weight).
// LDS: two swizzled bf16 activation tiles (x and h) + LN scratch.
__global__ __launch_bounds__(NTHR, 1)
void rnn_ln_fused(const float* __restrict__ X,
                  const float* __restrict__ W_ih,
                  const float* __restrict__ W_hh,
                  const float* __restrict__ b_ih,
                  const float* __restrict__ b_hh,
                  const float* __restrict__ ln_w,
                  const float* __restrict__ ln_b,
                  float* __restrict__ out)
{
    extern __shared__ char smem[];
    char*  xbuf = smem;                          // [32][256] bf16, XOR-swizzled
    char*  hbuf = smem + 16384;                  // [32][256] bf16, XOR-swizzled
    float* psum = (float*)(smem + 32768);        // [4 waves][32 rows][2]
    float* mrs  = (float*)(smem + 32768 + 1024); // [32 rows][2] (mean, rstd)

    const int tid = threadIdx.x;
    const int lane = tid & 63;
    const int wv  = tid >> 6;     // wave 0..3
    const int l15 = lane & 15;
    const int l4  = lane >> 4;    // 0..3
    const int n0  = blockIdx.x * ROWS;

    // ---- load weight fragments into registers (once) ----
    // B-frag for mfma_16x16x32: lane holds col j=l15, k = l4*8 + e (within kk*32 chunk)
    bf16x8 wih[8][4], whh[8][4];
    #pragma unroll
    for (int kk = 0; kk < 8; ++kk) {
        #pragma unroll
        for (int tc = 0; tc < 4; ++tc) {
            const int wr = wv*64 + tc*16 + l15;   // weight row = output col
            const int wk = kk*32 + l4*8;
            const float* p = W_ih + wr*FDIM + wk;
            const float* q = W_hh + wr*HDIM + wk;
            bf16x8 fi, fh;
            #pragma unroll
            for (int e = 0; e < 8; ++e) { fi[e] = f2bf(p[e]); fh[e] = f2bf(q[e]); }
            wih[kk][tc] = fi; whh[kk][tc] = fh;
        }
    }

    float bc[4], lw[4], lb[4];
    #pragma unroll
    for (int tc = 0; tc < 4; ++tc) {
        const int c = wv*64 + tc*16 + l15;
        bc[tc] = b_ih[c] + b_hh[c];   // per-step bias: b_ih (inside Xw) + b_hh
        lw[tc] = ln_w[c];
        lb[tc] = ln_b[c];
    }

    f32x4 acc[2][4];   // [row-tile][col-tile], C: col=l15, row=l4*4+j (+16*tr)
    f32x4 xld[8];      // staged X tile (f32), one step ahead of LDS

    auto load_x = [&](int t) {
        const f32x4* base = (const f32x4*)(X + ((size_t)t * NTOT + n0) * FDIM);
        #pragma unroll
        for (int k = 0; k < 8; ++k) xld[k] = base[k*256 + tid];  // fully coalesced
    };
    auto store_x = [&]() {   // cvt + swizzled ds_write_b64; row = 4k+wv, col = (tid&63)*4
        #pragma unroll
        for (int k = 0; k < 8; ++k) {
            const int row = 4*k + wv;
            int off = row*512 + (tid & 63)*8;
            off ^= (row & 7) << 4;
            unsigned lo = (unsigned)(unsigned short)f2bf(xld[k].x) |
                          ((unsigned)(unsigned short)f2bf(xld[k].y) << 16);
            unsigned hi = (unsigned)(unsigned short)f2bf(xld[k].z) |
                          ((unsigned)(unsigned short)f2bf(xld[k].w) << 16);
            uint2 v; v.x = lo; v.y = hi;
            *(uint2*)(xbuf + off) = v;
        }
    };
    auto mm = [&](const char* buf, const bf16x8 (&wf)[8][4]) {
        #pragma unroll
        for (int kk = 0; kk < 8; ++kk) {
            const int co = kk*64 + l4*16;           // byte offset of lane's k-chunk
            const int r0 = l15, r1 = l15 + 16;
            const int sw = (l15 & 7) << 4;          // r0&7 == r1&7
            bf16x8 a0 = *(const bf16x8*)(buf + ((r0*512 + co) ^ sw));
            bf16x8 a1 = *(const bf16x8*)(buf + ((r1*512 + co) ^ sw));
            #pragma unroll
            for (int tc = 0; tc < 4; ++tc) {
                acc[0][tc] = __builtin_amdgcn_mfma_f32_16x16x32_bf16(a0, wf[kk][tc], acc[0][tc], 0, 0, 0);
                acc[1][tc] = __builtin_amdgcn_mfma_f32_16x16x32_bf16(a1, wf[kk][tc], acc[1][tc], 0, 0, 0);
            }
        }
    };
    auto zero_acc = [&]() {
        #pragma unroll
        for (int tr = 0; tr < 2; ++tr)
            #pragma unroll
            for (int tc = 0; tc < 4; ++tc) acc[tr][tc] = f32x4{0.f, 0.f, 0.f, 0.f};
    };

    // ================= prologue =================
    load_x(0);
    store_x();
    __syncthreads();

    zero_acc();
    mm(xbuf, wih);            // acc = xw_0 = x_0 @ W_ih^T   (bias added later)
    load_x(1);
    __syncthreads();          // all waves done reading xbuf

    // h0 = xw_0 + b_ih + b_hh  (no relu) -> hbuf ; acc keeps xw_0
    #pragma unroll
    for (int tr = 0; tr < 2; ++tr)
        #pragma unroll
        for (int j = 0; j < 4; ++j) {
            const int row = tr*16 + l4*4 + j;
            const int rs = row*512, sw = (row & 7) << 4;
            #pragma unroll
            for (int tc = 0; tc < 4; ++tc) {
                const int col = wv*64 + tc*16 + l15;
                *(short*)(hbuf + ((rs + col*2) ^ sw)) = f2bf(acc[tr][tc][j] + bc[tc]);
            }
        }
    store_x();                // x_1 -> xbuf
    __syncthreads();

    // ================= main loop =================
    // invariants at top: hbuf = c_t, acc = xw_t, xbuf = x_{t+1} (if t<63)
    #pragma unroll 1
    for (int t = 0; t < TSTEPS; ++t) {
        if (t < 62) load_x(t + 2);          // prefetch a full step ahead

        mm(hbuf, whh);                      // acc = xw_t + c_t @ W_hh^T

        // c_{t+1} = relu(acc + bc), in place
        #pragma unroll
        for (int tr = 0; tr < 2; ++tr)
            #pragma unroll
            for (int tc = 0; tc < 4; ++tc) {
                f32x4 v = acc[tr][tc];
                #pragma unroll
                for (int j = 0; j < 4; ++j) v[j] = fmaxf(v[j] + bc[tc], 0.f);
                acc[tr][tc] = v;
            }

        // LN partials: per (tr,j) row, sum/sumsq over this wave's 64 cols
        float s[8], q[8];
        #pragma unroll
        for (int tr = 0; tr < 2; ++tr)
            #pragma unroll
            for (int j = 0; j < 4; ++j) {
                float a = 0.f, b = 0.f;
                #pragma unroll
                for (int tc = 0; tc < 4; ++tc) {
                    float v = acc[tr][tc][j];
                    a += v; b += v * v;
                }
                s[tr*4+j] = a; q[tr*4+j] = b;
            }
        #pragma unroll
        for (int m = 1; m < 16; m <<= 1) {
            #pragma unroll
            for (int i = 0; i < 8; ++i) {
                s[i] += __shfl_xor(s[i], m);
                q[i] += __shfl_xor(q[i], m);
            }
        }
        if (l15 == 0) {
            #pragma unroll
            for (int tr = 0; tr < 2; ++tr)
                #pragma unroll
                for (int j = 0; j < 4; ++j) {
                    const int row = tr*16 + l4*4 + j;
                    psum[(wv*32 + row)*2 + 0] = s[tr*4+j];
                    psum[(wv*32 + row)*2 + 1] = q[tr*4+j];
                }
        }
        __syncthreads();                    // (1) hbuf reads done; psum visible

        // write c_{t+1} -> hbuf (bf16, swizzled)
        #pragma unroll
        for (int tr = 0; tr < 2; ++tr)
            #pragma unroll
            for (int j = 0; j < 4; ++j) {
                const int row = tr*16 + l4*4 + j;
                const int rs = row*512, sw = (row & 7) << 4;
                #pragma unroll
                for (int tc = 0; tc < 4; ++tc) {
                    const int col = wv*64 + tc*16 + l15;
                    *(short*)(hbuf + ((rs + col*2) ^ sw)) = f2bf(acc[tr][tc][j]);
                }
            }
        // cross-wave LN finalize
        if (tid < 32) {
            float S = 0.f, Q = 0.f;
            #pragma unroll
            for (int k = 0; k < 4; ++k) {
                S += psum[(k*32 + tid)*2 + 0];
                Q += psum[(k*32 + tid)*2 + 1];
            }
            const float mean = S * (1.f/256.f);
            const float var  = Q * (1.f/256.f) - mean * mean;
            mrs[tid*2+0] = mean;
            mrs[tid*2+1] = rsqrtf(var + 1e-5f);
        }
        __syncthreads();                    // (2) mrs ready; hbuf written

        // normalize + store out[t]
        float* op = out + ((size_t)t * NTOT + n0) * HDIM;
        #pragma unroll
        for (int tr = 0; tr < 2; ++tr)
            #pragma unroll
            for (int j = 0; j < 4; ++j) {
                const int row = tr*16 + l4*4 + j;
                const float mean = mrs[row*2+0];
                const float rstd = mrs[row*2+1];
                #pragma unroll
                for (int tc = 0; tc < 4; ++tc) {
                    const int col = wv*64 + tc*16 + l15;
                    op[row*HDIM + col] = (acc[tr][tc][j] - mean) * rstd * lw[tc] + lb[tc];
                }
            }

        if (t < 63) {
            zero_acc();
            mm(xbuf, wih);                  // acc = xw_{t+1}
            if (t < 62) {
                __syncthreads();            // (3) xbuf reads done
                store_x();                  // x_{t+2} -> xbuf
            }
        }
    }
}

extern "C" void kernel_launch(void* const* d_in, const int* in_sizes, int n_in,
                              void* d_out, int out_size, void* d_ws, size_t ws_size,
                              hipStream_t stream) {
    const float* X   = (const float*)d_in[0];
    const float* Wih = (const float*)d_in[1];
    const float* Whh = (const float*)d_in[2];
    const float* bih = (const float*)d_in[3];
    const float* bhh = (const float*)d_in[4];
    const float* lnw = (const float*)d_in[5];
    const float* lnb = (const float*)d_in[6];
    float* out = (float*)d_out;

    const size_t shmem = 2*16384 + 1024 + 256;  // 33.25 KB
    rnn_ln_fused<<<dim3(NTOT / ROWS), dim3(NTHR), shmem, stream>>>(
        X, Wih, Whh, bih, bhh, lnw, lnb, out);
}